// Round 1
// baseline (1118.298 us; speedup 1.0000x reference)
//
#include <hip/hip_runtime.h>
#include <stdint.h>

// ---------------------------------------------------------------------------
// XlaQuantizedLinear: out[M,N] = (x[M,K] @ w[N,K]^T) * scaler[N]
//   x fp32, w int32 (int8-range values), out fp32.
//   M=8192, N=11008, K=4096 (derived from in_sizes; assumes tile-divisible).
// Strategy: convert x->bf16 and w->bf16 (exact for w) in d_ws, then m97-style
// 128x128 bf16 MFMA GEMM (B^T input) with global_load_lds width=16.
// Fallback (ws too small): same GEMM with reg-staged fp32/int32->bf16 convert.
// ---------------------------------------------------------------------------

typedef __attribute__((ext_vector_type(8))) short short8v;  // 8 bf16 (4 VGPRs)
typedef __attribute__((ext_vector_type(4))) short short4v;  // 4 bf16
typedef __attribute__((ext_vector_type(4))) float f32x4;    // MFMA acc

#define BM 128
#define BN 128
#define BK 32
#define NXCD 8

// fp32 -> bf16 bits, round-to-nearest-even (inputs are finite normals)
__device__ __forceinline__ short bf16_bits(float f) {
  uint32_t u = __builtin_bit_cast(uint32_t, f);
  uint32_t r = (u + 0x7FFFu + ((u >> 16) & 1u)) >> 16;
  return (short)r;
}

// async global->LDS, 16B per lane; LDS dest is wave-uniform base + lane*16
__device__ __forceinline__ void gl_lds16(const void* g, void* l) {
  __builtin_amdgcn_global_load_lds(
      (const __attribute__((address_space(1))) void*)g,
      (__attribute__((address_space(3))) void*)l,
      16, 0, 0);
}

// one K-step of compute: 8x ds_read_b128 + 16x mfma_f32_16x16x32_bf16
__device__ __forceinline__ void compute_step(const short* As, const short* Bs,
                                             int wr, int wc, int lane,
                                             f32x4 acc[4][4]) {
  const int ar = wr * 64 + (lane & 15);
  const int br = wc * 64 + (lane & 15);
  const int ko = (lane >> 4) * 8;
  short8v av[4], bv[4];
#pragma unroll
  for (int i = 0; i < 4; ++i) {
    av[i] = *(const short8v*)&As[(ar + i * 16) * BK + ko];
    bv[i] = *(const short8v*)&Bs[(br + i * 16) * BK + ko];
  }
#pragma unroll
  for (int mi = 0; mi < 4; ++mi)
#pragma unroll
    for (int ni = 0; ni < 4; ++ni)
      acc[mi][ni] = __builtin_amdgcn_mfma_f32_16x16x32_bf16(
          av[mi], bv[ni], acc[mi][ni], 0, 0, 0);
}

template <bool DIRECT>
__global__ __launch_bounds__(256) void gemm_bt(
    const void* __restrict__ Ap,   // DIRECT: bf16[M][K] else fp32[M][K]
    const void* __restrict__ Bp,   // DIRECT: bf16[N][K] else int32[N][K]
    const float* __restrict__ scaler, float* __restrict__ C,
    int M, int N, int K) {
  __shared__ alignas(16) short As[BM * BK];  // 8 KB
  __shared__ alignas(16) short Bs[BN * BK];  // 8 KB

  const int tid = threadIdx.x;
  const int lane = tid & 63;
  const int wid = tid >> 6;
  const int wr = wid >> 1, wc = wid & 1;

  // bijective XCD-aware swizzle (m204)
  const int nwg = gridDim.x;
  const int ntn = N / BN;
  {
  }
  int bid = blockIdx.x;
  int q = nwg / NXCD, r = nwg % NXCD;
  int xcd = bid % NXCD, idx = bid / NXCD;
  int swz = (xcd < r ? xcd * (q + 1) : r * (q + 1) + (xcd - r) * q) + idx;
  const int mt = swz / ntn, nt = swz % ntn;
  const int m0 = mt * BM, n0 = nt * BN;

  f32x4 acc[4][4] = {};
  const int kiters = K / BK;

  if constexpr (DIRECT) {
    const short* A = (const short*)Ap;
    const short* B = (const short*)Bp;
    // staging: per thread 2 gload_lds for A + 2 for B per K-step.
    // wave w instruction j covers LDS rows [j*64 + w*16, +16): lane i ->
    // row = j*64 + w*16 + (i>>2), 16B k-chunk = i&3.
    const int srow = wid * 16 + (lane >> 2);
    const int skc = lane & 3;
    const char* ag0 = (const char*)(A + (size_t)(m0 + srow) * K + skc * 8);
    const char* ag1 = ag0 + (size_t)64 * K * sizeof(short);
    const char* bg0 = (const char*)(B + (size_t)(n0 + srow) * K + skc * 8);
    const char* bg1 = bg0 + (size_t)64 * K * sizeof(short);
    char* al0 = (char*)As + wid * 1024;
    char* al1 = al0 + 4096;
    char* bl0 = (char*)Bs + wid * 1024;
    char* bl1 = bl0 + 4096;

    for (int kt = 0; kt < kiters; ++kt) {
      __syncthreads();  // previous compute done before overwrite
      gl_lds16(ag0, al0);
      gl_lds16(ag1, al1);
      gl_lds16(bg0, bl0);
      gl_lds16(bg1, bl1);
      ag0 += BK * 2; ag1 += BK * 2; bg0 += BK * 2; bg1 += BK * 2;
      __syncthreads();  // compiler drains vmcnt(0) before barrier
      compute_step(As, Bs, wr, wc, lane, acc);
    }
  } else {
    const float* A = (const float*)Ap;
    const int* B = (const int*)Bp;
    for (int kt = 0; kt < kiters; ++kt) {
      const int k0 = kt * BK;
      __syncthreads();
#pragma unroll
      for (int qq = 0; qq < 4; ++qq) {
        int chunk = qq * 256 + tid;       // 1024 float4-chunks per tile
        int row = chunk >> 3;             // 8 chunks of 4 elems per row
        int c4 = (chunk & 7) * 4;
        float4 va = *(const float4*)&A[(size_t)(m0 + row) * K + k0 + c4];
        int4 vb = *(const int4*)&B[(size_t)(n0 + row) * K + k0 + c4];
        short4v wa, wb;
        wa[0] = bf16_bits(va.x); wa[1] = bf16_bits(va.y);
        wa[2] = bf16_bits(va.z); wa[3] = bf16_bits(va.w);
        wb[0] = bf16_bits((float)vb.x); wb[1] = bf16_bits((float)vb.y);
        wb[2] = bf16_bits((float)vb.z); wb[3] = bf16_bits((float)vb.w);
        *(short4v*)&As[row * BK + c4] = wa;
        *(short4v*)&Bs[row * BK + c4] = wb;
      }
      __syncthreads();
      compute_step(As, Bs, wr, wc, lane, acc);
    }
  }

  // epilogue: C/D layout col=lane&15, row=(lane>>4)*4+j (m89/m91)
  float sc[4];
  const int cc0 = n0 + wc * 64 + (lane & 15);
#pragma unroll
  for (int ni = 0; ni < 4; ++ni) sc[ni] = scaler[cc0 + ni * 16];
  const int cr0 = m0 + wr * 64 + ((lane >> 4) << 2);
#pragma unroll
  for (int mi = 0; mi < 4; ++mi)
#pragma unroll
    for (int j = 0; j < 4; ++j) {
      float* crow = C + (size_t)(cr0 + mi * 16 + j) * N;
#pragma unroll
      for (int ni = 0; ni < 4; ++ni)
        crow[cc0 + ni * 16] = acc[mi][ni][j] * sc[ni];
    }
}

// ---- conversion pre-passes (vectorized, grid-stride) -----------------------
__global__ void cvt_f32_bf16(const float* __restrict__ in,
                             short* __restrict__ out, long long n8) {
  long long i = (long long)blockIdx.x * blockDim.x + threadIdx.x;
  const long long stride = (long long)gridDim.x * blockDim.x;
  for (; i < n8; i += stride) {
    const float4* p = (const float4*)(in + i * 8);
    float4 a = p[0], b = p[1];
    short8v o;
    o[0] = bf16_bits(a.x); o[1] = bf16_bits(a.y);
    o[2] = bf16_bits(a.z); o[3] = bf16_bits(a.w);
    o[4] = bf16_bits(b.x); o[5] = bf16_bits(b.y);
    o[6] = bf16_bits(b.z); o[7] = bf16_bits(b.w);
    *(short8v*)(out + i * 8) = o;
  }
}

__global__ void cvt_i32_bf16(const int* __restrict__ in,
                             short* __restrict__ out, long long n8) {
  long long i = (long long)blockIdx.x * blockDim.x + threadIdx.x;
  const long long stride = (long long)gridDim.x * blockDim.x;
  for (; i < n8; i += stride) {
    const int4* p = (const int4*)(in + i * 8);
    int4 a = p[0], b = p[1];
    short8v o;
    o[0] = bf16_bits((float)a.x); o[1] = bf16_bits((float)a.y);
    o[2] = bf16_bits((float)a.z); o[3] = bf16_bits((float)a.w);
    o[4] = bf16_bits((float)b.x); o[5] = bf16_bits((float)b.y);
    o[6] = bf16_bits((float)b.z); o[7] = bf16_bits((float)b.w);
    *(short8v*)(out + i * 8) = o;
  }
}

extern "C" void kernel_launch(void* const* d_in, const int* in_sizes, int n_in,
                              void* d_out, int out_size, void* d_ws,
                              size_t ws_size, hipStream_t stream) {
  const float* x = (const float*)d_in[0];       // [M][K] fp32
  const int* w = (const int*)d_in[1];           // [N][K] int32 (int8 range)
  const float* sc = (const float*)d_in[2];      // [N] fp32
  float* out = (float*)d_out;                   // [M][N] fp32

  const long long xn = in_sizes[0];             // M*K
  const long long wn = in_sizes[1];             // N*K
  const int N = in_sizes[2];
  const int K = (int)(wn / N);
  const int M = (int)(xn / K);
  const int grid = (M / BM) * (N / BN);

  const size_t need = (size_t)(xn + wn) * sizeof(short);
  if (ws_size >= need) {
    short* xb = (short*)d_ws;                   // bf16 x
    short* wb = xb + xn;                        // bf16 w
    cvt_f32_bf16<<<2048, 256, 0, stream>>>(x, xb, xn / 8);
    cvt_i32_bf16<<<2048, 256, 0, stream>>>(w, wb, wn / 8);
    gemm_bt<true><<<grid, 256, 0, stream>>>(xb, wb, sc, out, M, N, K);
  } else {
    gemm_bt<false><<<grid, 256, 0, stream>>>(x, w, sc, out, M, N, K);
  }
}

// Round 2
// 753.605 us; speedup vs baseline: 1.4839x; 1.4839x over previous
//
#include <hip/hip_runtime.h>
#include <stdint.h>

// ---------------------------------------------------------------------------
// XlaQuantizedLinear: out[M,N] = (x[M,K] @ w[N,K]^T) * scaler[N]
// Round 2: 256x256 8-phase deep-pipelined bf16 MFMA GEMM (m201 template):
//   - 8 waves (2Mx4N), BK=64, 128KB LDS double-buffer
//   - region-permuted LDS layout; one 16KB region staged per phase
//   - counted vmcnt(4) per phase (never drain to 0 in main loop)
//   - raw s_barrier (no __syncthreads vmcnt(0) drain), sched_barrier fences
//   - XOR swizzle ((row&7)<<4) both-sides (pre-swizzled global source)
//   - s_setprio(1) around MFMA clusters
// Pre-passes convert x(fp32)->bf16 and w(int32)->bf16 (exact) into d_ws.
// ---------------------------------------------------------------------------

typedef __attribute__((ext_vector_type(8))) short short8v;  // 8 bf16
typedef __attribute__((ext_vector_type(4))) short short4v;
typedef __attribute__((ext_vector_type(4))) float f32x4;

#define NXCD 8

__device__ __forceinline__ short bf16_bits(float f) {
  uint32_t u = __builtin_bit_cast(uint32_t, f);
  uint32_t r = (u + 0x7FFFu + ((u >> 16) & 1u)) >> 16;
  return (short)r;
}

__device__ __forceinline__ void gl_lds16(const void* g, void* l) {
  __builtin_amdgcn_global_load_lds(
      (const __attribute__((address_space(1))) void*)g,
      (__attribute__((address_space(3))) void*)l, 16, 0, 0);
}

// ---------------- 256x256 8-phase kernel ------------------------------------
// LDS map (128KB): A(buf) at buf*65536 (32KB: [256 rows][128B]),
//                  B(buf) at 32768+buf*65536.
// A lds_row = mh*128 + wr*64 + r   (block A-row = wr*128 + mh*64 + r, r<64)
// B lds_row = nh*128 + wc*32 + r   (block B-row = wc*64 + nh*32 + r, r<32)
// swizzle: physical kbyte = logical kbyte ^ ((lds_row&7)<<4)  (involution)

__global__ __launch_bounds__(512, 2) void gemm256(
    const short* __restrict__ A, const short* __restrict__ B,
    const float* __restrict__ scaler, float* __restrict__ C,
    int M, int N, int K) {
  __shared__ alignas(16) char sm[131072];

  const int tid = threadIdx.x;
  const int l = tid & 63;
  const int w = tid >> 6;
  const int wr = w >> 2, wc = w & 3;
  const int ln15 = l & 15;

  // bijective XCD-aware swizzle (m204)
  const int nwg = gridDim.x;
  const int ntn = N >> 8;
  int bid = blockIdx.x;
  int q = nwg / NXCD, rr = nwg % NXCD;
  int xcd = bid % NXCD, idx = bid / NXCD;
  int swz = (xcd < rr ? xcd * (q + 1) : rr * (q + 1) + (xcd - rr) * q) + idx;
  const int m0 = (swz / ntn) << 8, n0 = (swz % ntn) << 8;

  const size_t ldkb = (size_t)K * 2;

  // --- staging per-thread bases (source pre-swizzled: rule 21) ---
  const int srow8 = l >> 3;                       // row-within-8 this lane fills
  const int sswz = ((l & 7) ^ srow8) << 4;        // inverse-swizzled src kbyte
  const char* Ag = (const char*)A + (size_t)(m0 + w * 8 + srow8) * ldkb + sswz;
  const char* Bg = (const char*)B +
      (size_t)(n0 + (w >> 2) * 64 + (w & 3) * 8 + srow8) * ldkb + sswz;

  // --- read-side swizzled k offsets (row&7 == l&7 for all frag reads) ---
  const int swzc = (l & 7) << 4;
  const int klo = (l >> 4) << 4;                  // 16B k-chunk, bits 4-5
  const int e45 = klo ^ (swzc & 48);
  const int s6 = swzc & 64;
  const int kof0 = e45 | s6;                      // ks=0 physical kbyte
  const int kof1 = e45 | (64 ^ s6);               // ks=1 physical kbyte

  f32x4 acc[8][4] = {};                           // [mf][ng], 128 VGPR
  short8v a[8], b0[4], b1[4];

  const int NT = K >> 6;                          // K-tiles (even)

#define LDA8(buf, mh, dst) do {                                               \
    const char* _b = sm + (buf) * 65536 + ((mh)*128 + wr*64 + ln15) * 128;    \
    _Pragma("unroll") for (int f = 0; f < 4; ++f) {                           \
      dst[f*2+0] = *(const short8v*)(_b + f*2048 + kof0);                     \
      dst[f*2+1] = *(const short8v*)(_b + f*2048 + kof1); } } while (0)

#define LDB4(buf, nh, dst) do {                                               \
    const char* _b = sm + 32768 + (buf)*65536 + ((nh)*128 + wc*32 + ln15)*128;\
    _Pragma("unroll") for (int nf = 0; nf < 2; ++nf) {                        \
      dst[nf*2+0] = *(const short8v*)(_b + nf*2048 + kof0);                   \
      dst[nf*2+1] = *(const short8v*)(_b + nf*2048 + kof1); } } while (0)

#define STAGEA(buf, mh, tb) do {                                              \
    gl_lds16(Ag + (size_t)((mh)*64) * ldkb + (tb),                            \
             sm + (buf)*65536 + (mh)*16384 + w*1024);                         \
    gl_lds16(Ag + (size_t)((mh)*64 + 128) * ldkb + (tb),                      \
             sm + (buf)*65536 + (mh)*16384 + 8192 + w*1024); } while (0)

#define STAGEB(buf, nh, tb) do {                                              \
    gl_lds16(Bg + (size_t)((nh)*32) * ldkb + (tb),                            \
             sm + 32768 + (buf)*65536 + (nh)*16384 + w*1024);                 \
    gl_lds16(Bg + (size_t)((nh)*32 + 128) * ldkb + (tb),                      \
             sm + 32768 + (buf)*65536 + (nh)*16384 + 8192 + w*1024); } while (0)

#define MMAQ(mh, nh, av, bv) do {                                             \
    __builtin_amdgcn_s_setprio(1);                                            \
    _Pragma("unroll") for (int f = 0; f < 4; ++f)                             \
    _Pragma("unroll") for (int nf = 0; nf < 2; ++nf)                          \
    _Pragma("unroll") for (int ks = 0; ks < 2; ++ks)                          \
      acc[(mh)*4+f][(nh)*2+nf] = __builtin_amdgcn_mfma_f32_16x16x32_bf16(     \
          av[f*2+ks], bv[nf*2+ks], acc[(mh)*4+f][(nh)*2+nf], 0, 0, 0);        \
    __builtin_amdgcn_s_setprio(0); } while (0)

#define BAR() do { __builtin_amdgcn_sched_barrier(0);                         \
    asm volatile("s_barrier" ::: "memory");                                   \
    __builtin_amdgcn_sched_barrier(0); } while (0)

#define VMW(nxf) do {                                                         \
    if (nxf) asm volatile("s_waitcnt vmcnt(4)" ::: "memory");                 \
    else     asm volatile("s_waitcnt vmcnt(0)" ::: "memory"); } while (0)

  // prologue: stage K-tile 0 into buf0, full drain once
  STAGEA(0, 0, 0); STAGEA(0, 1, 0); STAGEB(0, 0, 0); STAGEB(0, 1, 0);
  asm volatile("s_waitcnt vmcnt(0)" ::: "memory");
  BAR();

  for (int t = 0; t < NT; t += 2) {
    const bool nx = (t + 2) < NT;
    const size_t tb1 = (size_t)(t + 1) << 7;      // buf1 <- tile t+1
    const size_t tb2 = (size_t)(t + 2) << 7;      // buf0 <- tile t+2
    // P1: quadrant (0,0) of buf0; stage buf1.A-mh0  (read at P5, gap 4)
    LDA8(0, 0, a); LDB4(0, 0, b0);
    STAGEA(1, 0, tb1);
    VMW(nx); BAR();
    MMAQ(0, 0, a, b0);
    BAR();
    // P2: (0,1); stage buf1.B-nh0 (read P5, gap 3)
    LDB4(0, 1, b1);
    STAGEB(1, 0, tb1);
    VMW(nx); BAR();
    MMAQ(0, 1, a, b1);
    BAR();
    // P3: (1,0); stage buf1.B-nh1 (read P6, gap 3)
    LDA8(0, 1, a);
    STAGEB(1, 1, tb1);
    VMW(nx); BAR();
    MMAQ(1, 0, a, b0);
    BAR();
    // P4: (1,1); stage buf1.A-mh1 (read P7, gap 3)
    STAGEA(1, 1, tb1);
    VMW(nx); BAR();
    MMAQ(1, 1, a, b1);
    BAR();
    // P5: (0,0) of buf1; stage buf0.A-mh0 <- tile t+2 (read next P1, gap 4)
    LDA8(1, 0, a); LDB4(1, 0, b0);
    if (nx) STAGEA(0, 0, tb2);
    VMW(nx); BAR();
    MMAQ(0, 0, a, b0);
    BAR();
    // P6: (0,1); stage buf0.B-nh0 (read next P1, gap 3)
    LDB4(1, 1, b1);
    if (nx) STAGEB(0, 0, tb2);
    VMW(nx); BAR();
    MMAQ(0, 1, a, b1);
    BAR();
    // P7: (1,0); stage buf0.B-nh1 (read next P2, gap 3)
    LDA8(1, 1, a);
    if (nx) STAGEB(0, 1, tb2);
    VMW(nx); BAR();
    MMAQ(1, 0, a, b0);
    BAR();
    // P8: (1,1); stage buf0.A-mh1 (read next P3, gap 3)
    if (nx) STAGEA(0, 1, tb2);
    VMW(nx); BAR();
    MMAQ(1, 1, a, b1);
    BAR();
  }

  // epilogue: C row = m0+wr*128+mh*64+f*16+(l>>4)*4+j; col = n0+wc*64+nh*32+nf*16+ln15
  float scl[4];
#pragma unroll
  for (int ng = 0; ng < 4; ++ng)
    scl[ng] = scaler[n0 + wc * 64 + (ng >> 1) * 32 + (ng & 1) * 16 + ln15];
  const int row0 = m0 + wr * 128 + ((l >> 4) << 2);
  const int col0 = n0 + wc * 64 + ln15;
#pragma unroll
  for (int mf = 0; mf < 8; ++mf) {
    const int rbase = row0 + (mf >> 2) * 64 + (mf & 3) * 16;
#pragma unroll
    for (int j = 0; j < 4; ++j) {
      float* cp = C + (size_t)(rbase + j) * N + col0;
#pragma unroll
      for (int ng = 0; ng < 4; ++ng)
        cp[(ng >> 1) * 32 + (ng & 1) * 16] = acc[mf][ng][j] * scl[ng];
    }
  }
#undef LDA8
#undef LDB4
#undef STAGEA
#undef STAGEB
#undef MMAQ
#undef BAR
#undef VMW
}

// ---------------- fallback (round-1, no workspace needed) -------------------
#define FBM 128
#define FBN 128
#define FBK 32

__global__ __launch_bounds__(256) void gemm_fb(
    const float* __restrict__ A, const int* __restrict__ B,
    const float* __restrict__ scaler, float* __restrict__ C,
    int M, int N, int K) {
  __shared__ alignas(16) short As[FBM * FBK];
  __shared__ alignas(16) short Bs[FBN * FBK];

  const int tid = threadIdx.x;
  const int lane = tid & 63;
  const int wid = tid >> 6;
  const int wr = wid >> 1, wc = wid & 1;

  const int nwg = gridDim.x;
  const int ntn = N / FBN;
  int bid = blockIdx.x;
  int q = nwg / NXCD, r = nwg % NXCD;
  int xcd = bid % NXCD, idx = bid / NXCD;
  int swz = (xcd < r ? xcd * (q + 1) : r * (q + 1) + (xcd - r) * q) + idx;
  const int mt = swz / ntn, nt = swz % ntn;
  const int m0 = mt * FBM, n0 = nt * FBN;

  f32x4 acc[4][4] = {};
  const int kiters = K / FBK;

  for (int kt = 0; kt < kiters; ++kt) {
    const int k0 = kt * FBK;
    __syncthreads();
#pragma unroll
    for (int qq = 0; qq < 4; ++qq) {
      int chunk = qq * 256 + tid;
      int row = chunk >> 3;
      int c4 = (chunk & 7) * 4;
      float4 va = *(const float4*)&A[(size_t)(m0 + row) * K + k0 + c4];
      int4 vb = *(const int4*)&B[(size_t)(n0 + row) * K + k0 + c4];
      short4v wa, wb;
      wa[0] = bf16_bits(va.x); wa[1] = bf16_bits(va.y);
      wa[2] = bf16_bits(va.z); wa[3] = bf16_bits(va.w);
      wb[0] = bf16_bits((float)vb.x); wb[1] = bf16_bits((float)vb.y);
      wb[2] = bf16_bits((float)vb.z); wb[3] = bf16_bits((float)vb.w);
      *(short4v*)&As[row * FBK + c4] = wa;
      *(short4v*)&Bs[row * FBK + c4] = wb;
    }
    __syncthreads();
    const int ar = wr * 64 + (lane & 15);
    const int br = wc * 64 + (lane & 15);
    const int ko = (lane >> 4) * 8;
    short8v av[4], bv[4];
#pragma unroll
    for (int i = 0; i < 4; ++i) {
      av[i] = *(const short8v*)&As[(ar + i * 16) * FBK + ko];
      bv[i] = *(const short8v*)&Bs[(br + i * 16) * FBK + ko];
    }
#pragma unroll
    for (int mi = 0; mi < 4; ++mi)
#pragma unroll
      for (int ni = 0; ni < 4; ++ni)
        acc[mi][ni] = __builtin_amdgcn_mfma_f32_16x16x32_bf16(
            av[mi], bv[ni], acc[mi][ni], 0, 0, 0);
  }

  float sc[4];
  const int cc0 = n0 + wc * 64 + (lane & 15);
#pragma unroll
  for (int ni = 0; ni < 4; ++ni) sc[ni] = scaler[cc0 + ni * 16];
  const int cr0 = m0 + wr * 64 + ((lane >> 4) << 2);
#pragma unroll
  for (int mi = 0; mi < 4; ++mi)
#pragma unroll
    for (int j = 0; j < 4; ++j) {
      float* crow = C + (size_t)(cr0 + mi * 16 + j) * N;
#pragma unroll
      for (int ni = 0; ni < 4; ++ni)
        crow[cc0 + ni * 16] = acc[mi][ni][j] * sc[ni];
    }
}

// ---- conversion pre-passes (vectorized, grid-stride) -----------------------
__global__ void cvt_f32_bf16(const float* __restrict__ in,
                             short* __restrict__ out, long long n8) {
  long long i = (long long)blockIdx.x * blockDim.x + threadIdx.x;
  const long long stride = (long long)gridDim.x * blockDim.x;
  for (; i < n8; i += stride) {
    const float4* p = (const float4*)(in + i * 8);
    float4 va = p[0], vb = p[1];
    short8v o;
    o[0] = bf16_bits(va.x); o[1] = bf16_bits(va.y);
    o[2] = bf16_bits(va.z); o[3] = bf16_bits(va.w);
    o[4] = bf16_bits(vb.x); o[5] = bf16_bits(vb.y);
    o[6] = bf16_bits(vb.z); o[7] = bf16_bits(vb.w);
    *(short8v*)(out + i * 8) = o;
  }
}

__global__ void cvt_i32_bf16(const int* __restrict__ in,
                             short* __restrict__ out, long long n8) {
  long long i = (long long)blockIdx.x * blockDim.x + threadIdx.x;
  const long long stride = (long long)gridDim.x * blockDim.x;
  for (; i < n8; i += stride) {
    const int4* p = (const int4*)(in + i * 8);
    int4 va = p[0], vb = p[1];
    short8v o;
    o[0] = bf16_bits((float)va.x); o[1] = bf16_bits((float)va.y);
    o[2] = bf16_bits((float)va.z); o[3] = bf16_bits((float)va.w);
    o[4] = bf16_bits((float)vb.x); o[5] = bf16_bits((float)vb.y);
    o[6] = bf16_bits((float)vb.z); o[7] = bf16_bits((float)vb.w);
    *(short8v*)(out + i * 8) = o;
  }
}

extern "C" void kernel_launch(void* const* d_in, const int* in_sizes, int n_in,
                              void* d_out, int out_size, void* d_ws,
                              size_t ws_size, hipStream_t stream) {
  const float* x = (const float*)d_in[0];       // [M][K] fp32
  const int* w = (const int*)d_in[1];           // [N][K] int32 (int8 range)
  const float* sc = (const float*)d_in[2];      // [N] fp32
  float* out = (float*)d_out;                   // [M][N] fp32

  const long long xn = in_sizes[0];             // M*K
  const long long wn = in_sizes[1];             // N*K
  const int N = in_sizes[2];
  const int K = (int)(wn / N);
  const int M = (int)(xn / K);

  const size_t need = (size_t)(xn + wn) * sizeof(short);
  const bool ok256 = (M % 256 == 0) && (N % 256 == 0) && (K % 128 == 0);

  if (ws_size >= need && ok256) {
    short* xb = (short*)d_ws;                   // bf16 x
    short* wb = xb + xn;                        // bf16 w
    cvt_f32_bf16<<<2048, 256, 0, stream>>>(x, xb, xn / 8);
    cvt_i32_bf16<<<2048, 256, 0, stream>>>(w, wb, wn / 8);
    const int grid = (M / 256) * (N / 256);
    gemm256<<<grid, 512, 0, stream>>>(xb, wb, sc, out, M, N, K);
  } else {
    const int grid = (M / FBM) * (N / FBN);
    gemm_fb<<<grid, 256, 0, stream>>>(x, w, sc, out, M, N, K);
  }
}